// Round 1
// baseline (1204.024 us; speedup 1.0000x reference)
//
#include <hip/hip_runtime.h>

#define RN      128
#define START_T 126
#define END_T   127
#define CH      3      // emission chunk: steps per producer/consumer handoff
#define NSEQ    16     // sequences per block (= MFMA columns)

typedef short v8s __attribute__((ext_vector_type(8)));   // 8 x bf16 MFMA A/B frag
typedef float v4f __attribute__((ext_vector_type(4)));   // 4 x f32 MFMA C/D frag

__device__ __forceinline__ unsigned short f2bf(float f){
    unsigned u = __float_as_uint(f);
    u += 0x7fffu + ((u>>16)&1u);
    return (unsigned short)(u>>16);
}
__device__ __forceinline__ float bf2f(unsigned short s){
    return __uint_as_float(((unsigned)s)<<16);
}
// pack two f32 -> 2 x bf16 in one dword (RNE)
__device__ __forceinline__ unsigned cvt_pk_bf16(float lo, float hi){
    unsigned r;
    asm("v_cvt_pk_bf16_f32 %0, %1, %2" : "=v"(r) : "v"(lo), "v"(hi));
    return r;
}

// Wave 0: consumer (serial recurrence, 16 seqs across MFMA columns).
// Waves 1,2: producers (stream X, exp, stage into LDS chunks).
__global__ __launch_bounds__(192, 1)
void crf_nll_kernel(const float* __restrict__ X,
                    const int*   __restrict__ y,
                    const float* __restrict__ trans,
                    float* __restrict__ out, int L, int B)
{
    const int g    = blockIdx.x;
    const int tid  = threadIdx.x;
    const int w    = tid >> 6;
    const int lane = tid & 63;
    const int b0   = g * NSEQ;

    // emis[buf][s][n][k] f32, k-bytes XOR-swizzled by ((n&7)<<4)   : 48 KB
    __shared__ __align__(16) float          emis[2][CH][NSEQ][RN];
    // pbuf[buf][n][k] bf16, k-bytes XOR-swizzled by ((n&7)<<4)     :  8 KB
    __shared__ __align__(16) unsigned short pbuf[2][NSEQ][RN];
    __shared__ float goldsh[NSEQ];

    const int nch = (L + CH - 1) / CH;

    // ---------------- common prologue: gold score + p init ----------------
    if (tid < NSEQ) goldsh[tid] = 0.f;
    {
        unsigned short* pr = &pbuf[0][0][0];
        for (int i = tid; i < 2*NSEQ*RN; i += 192) pr[i] = 0;
    }
    __syncthreads();
    {
        const int n = tid & 15, stripe = tid >> 4;   // 12 t-stripes x 16 seqs
        int b = b0 + n; if (b >= B) b = B - 1;
        const int*   yb = y + (size_t)b * L;
        const float* Xb = X + (size_t)b * L * RN;
        float gacc = 0.f;
        for (int t = stripe; t < L; t += 12) {
            int yt = yb[t];
            int yp = t ? yb[t-1] : START_T;
            gacc += trans[yt*RN + yp] + Xb[(size_t)t*RN + yt];
        }
        if (stripe == 0) gacc += trans[END_T*RN + yb[L-1]];
        atomicAdd(&goldsh[n], gacc);
    }
    if (tid < NSEQ) {   // seed p0[n][START] = 1.0 (swizzled position)
        char* base = (char*)&pbuf[0][0][0];
        *(unsigned short*)(base + (tid<<8) + ((2*START_T) ^ ((tid&7)<<4))) = (unsigned short)0x3F80;
    }
    __syncthreads();

    if (w == 0) {
        // ========================= CONSUMER =========================
        const int n = lane & 15;      // MFMA column = sequence within group
        const int q = lane >> 4;      // k/row quad
        const int x = (n & 7) << 4;   // LDS swizzle

        // E = exp(trans) A-frags resident in VGPRs: A[m=16T+n][k=32c+8q+j]
        v8s Ef[8][4];
        #pragma unroll
        for (int T = 0; T < 8; ++T) {
            #pragma unroll
            for (int cc = 0; cc < 4; ++cc) {
                const float* tr = trans + (size_t)(16*T + n)*RN + 32*cc + 8*q;
                float4 u0 = *(const float4*)(tr);
                float4 u1 = *(const float4*)(tr + 4);
                v8s v;
                v[0]=(short)f2bf(__expf(u0.x)); v[1]=(short)f2bf(__expf(u0.y));
                v[2]=(short)f2bf(__expf(u0.z)); v[3]=(short)f2bf(__expf(u0.w));
                v[4]=(short)f2bf(__expf(u1.x)); v[5]=(short)f2bf(__expf(u1.y));
                v[6]=(short)f2bf(__expf(u1.z)); v[7]=(short)f2bf(__expf(u1.w));
                Ef[T][cc] = v;
            }
        }

        // precomputed lane-invariant LDS byte offsets (XOR split into disjoint bit fields)
        int prd[4], pwr[8], eof[8];
        #pragma unroll
        for (int cc = 0; cc < 4; ++cc)                    // read k=32cc+8q (16B)
            prd[cc] = n*256 + (64*cc ^ (x & 64)) + ((16*q) ^ (x & 48));
        #pragma unroll
        for (int T = 0; T < 8; ++T) {
            pwr[T] = n*256 + (32*T ^ (x & 0x60)) + ((8*q) ^ (x & 0x10)); // write k=16T+4q (8B)
            eof[T] = n*512 + (64*T ^ (x & 64)) + ((16*q) ^ (x & 48));    // emis k=16T+4q (16B f32)
        }

        char* pb_base = (char*)&pbuf[0][0][0];
        char* em_base = (char*)&emis[0][0][0][0];

        float logscale = 0.f, mxf = 1.f, invv = 1.f;

        for (int c = 0; c < nch; ++c) {
            asm volatile("" ::: "memory");
            __builtin_amdgcn_s_barrier();          // chunk c staged by producers
            asm volatile("" ::: "memory");
            char* emc = em_base + (c & 1) * (CH*NSEQ*RN*4);
            #pragma unroll
            for (int s = 0; s < CH; ++s) {
                const int t = c*CH + s;
                if (t >= L) break;
                char* prb = pb_base + (t & 1) * 4096;
                char* pwb = pb_base + ((t + 1) & 1) * 4096;
                char* emb = emc + s * (NSEQ*RN*4);

                v8s Bf0 = *(const v8s*)(prb + prd[0]);
                v8s Bf1 = *(const v8s*)(prb + prd[1]);
                v8s Bf2 = *(const v8s*)(prb + prd[2]);
                v8s Bf3 = *(const v8s*)(prb + prd[3]);

                float4 ev[8];
                #pragma unroll
                for (int T = 0; T < 8; ++T)
                    ev[T] = *(const float4*)(emb + eof[T]);

                v4f acc[8];
                #pragma unroll
                for (int T = 0; T < 8; ++T) acc[T] = (v4f){0.f,0.f,0.f,0.f};
                // c-outer / T-inner: 8 independent chains -> MFMA latency hidden by issue breadth
                #pragma unroll
                for (int T = 0; T < 8; ++T) acc[T] = __builtin_amdgcn_mfma_f32_16x16x32_bf16(Ef[T][0], Bf0, acc[T], 0,0,0);
                #pragma unroll
                for (int T = 0; T < 8; ++T) acc[T] = __builtin_amdgcn_mfma_f32_16x16x32_bf16(Ef[T][1], Bf1, acc[T], 0,0,0);
                #pragma unroll
                for (int T = 0; T < 8; ++T) acc[T] = __builtin_amdgcn_mfma_f32_16x16x32_bf16(Ef[T][2], Bf2, acc[T], 0,0,0);
                #pragma unroll
                for (int T = 0; T < 8; ++T) acc[T] = __builtin_amdgcn_mfma_f32_16x16x32_bf16(Ef[T][3], Bf3, acc[T], 0,0,0);

                const bool mstep = ((t & 3) == 1);   // measure per-column max
                const bool astep = ((t & 3) == 2);   // apply (stale-by-one)
                if (astep) { invv = 1.0f / mxf; logscale += __logf(mxf); }
                float vmax = 0.f;
                #pragma unroll
                for (int T = 0; T < 8; ++T) {
                    float o0 = acc[T][0] * ev[T].x;
                    float o1 = acc[T][1] * ev[T].y;
                    float o2 = acc[T][2] * ev[T].z;
                    float o3 = acc[T][3] * ev[T].w;
                    if (astep) { o0 *= invv; o1 *= invv; o2 *= invv; o3 *= invv; }
                    if (mstep) vmax = fmaxf(vmax, fmaxf(fmaxf(o0,o1), fmaxf(o2,o3)));
                    uint2 dd;
                    dd.x = cvt_pk_bf16(o0, o1);
                    dd.y = cvt_pk_bf16(o2, o3);
                    *(uint2*)(pwb + pwr[T]) = dd;    // ds_write_b64, swizzled
                }
                if (mstep) {   // per-column (per-sequence) max across the 4 quads
                    float m1 = fmaxf(vmax, __shfl_xor(vmax, 16, 64));
                    mxf = fmaxf(m1, __shfl_xor(m1, 32, 64));
                }
            }
        }

        // ---------------- logZ epilogue ----------------
        char* pfbase = pb_base + (L & 1) * 4096;
        float zacc = 0.f;
        #pragma unroll
        for (int u = 0; u < 4; ++u) {
            int off = n*256 + (64*q ^ (x & 64)) + ((16*u) ^ (x & 48));
            v8s pv = *(const v8s*)(pfbase + off);
            #pragma unroll
            for (int j = 0; j < 8; ++j) {
                int k = 32*q + 8*u + j;
                zacc += bf2f((unsigned short)pv[j]) * __expf(trans[END_T*RN + k]);
            }
        }
        zacc += __shfl_xor(zacc, 16, 64);
        zacc += __shfl_xor(zacc, 32, 64);
        if (q == 0 && (b0 + n) < B)
            out[b0 + n] = logscale + __logf(zacc) - goldsh[n];
    } else {
        // ========================= PRODUCERS (w = 1,2) =========================
        const int pidx = w - 1;
        float4 RA[12], RB[12];    // two chunks in flight (covers ~900cy HBM latency)

        auto issue_chunk = [&](int c, float4* R) {
            #pragma unroll
            for (int i = 0; i < 12; ++i) {
                int f  = i*128 + pidx*64 + lane;            // (s,n,tq) flat over CH*16*32
                int s  = f >> 9, rem = f & 511, nn = rem >> 5, tq = rem & 31;
                int t  = c*CH + s; if (t >= L) t = L - 1;   // clamped tail (unused)
                int b  = b0 + nn; if (b >= B) b = B - 1;
                R[i] = *(const float4*)(X + (size_t)b*L*RN + (size_t)t*RN + 4*tq);
            }
        };
        auto expwrite_chunk = [&](int c, const float4* R) {
            char* emc = (char*)&emis[0][0][0][0] + (c & 1)*(CH*NSEQ*RN*4);
            #pragma unroll
            for (int i = 0; i < 12; ++i) {
                int f  = i*128 + pidx*64 + lane;
                int s  = f >> 9, rem = f & 511, nn = rem >> 5, tq = rem & 31;
                float4 v = R[i];
                float4 e;
                e.x = __expf(v.x); e.y = __expf(v.y);
                e.z = __expf(v.z); e.w = __expf(v.w);
                *(float4*)(emc + s*(NSEQ*RN*4) + nn*512 + ((16*tq) ^ ((nn&7)<<4))) = e;
            }
        };

        issue_chunk(0, RA);
        if (nch > 1) issue_chunk(1, RB);
        expwrite_chunk(0, RA);

        for (int c = 0; c < nch; ++c) {
            // drain only LDS (writes visible to consumer); vmcnt prefetch stays in flight
            asm volatile("s_waitcnt lgkmcnt(0)" ::: "memory");
            __builtin_amdgcn_s_barrier();
            asm volatile("" ::: "memory");
            if (c + 2 < nch) issue_chunk(c + 2, (c & 1) ? RB : RA);
            if (c + 1 < nch) expwrite_chunk(c + 1, (c & 1) ? RA : RB);
        }
    }
}

extern "C" void kernel_launch(void* const* d_in, const int* in_sizes, int n_in,
                              void* d_out, int out_size, void* d_ws, size_t ws_size,
                              hipStream_t stream) {
    const float* X     = (const float*)d_in[0];
    const int*   y     = (const int*)d_in[1];
    const float* trans = (const float*)d_in[2];
    float*       out   = (float*)d_out;

    const int B = out_size;            // 256
    const int L = in_sizes[1] / B;     // 1024

    const int blocks = (B + NSEQ - 1) / NSEQ;   // 16
    crf_nll_kernel<<<dim3(blocks), dim3(192), 0, stream>>>(X, y, trans, out, L, B);
}

// Round 2
// 1126.283 us; speedup vs baseline: 1.0690x; 1.0690x over previous
//
#include <hip/hip_runtime.h>

#define RN      128
#define START_T 126
#define END_T   127
#define CH      3      // emission chunk: steps per producer/consumer handoff
#define NSEQ    16     // sequences per block (= MFMA columns)

typedef short v8s __attribute__((ext_vector_type(8)));   // 8 x bf16 MFMA A/B frag
typedef float v4f __attribute__((ext_vector_type(4)));   // 4 x f32 MFMA C/D frag

__device__ __forceinline__ unsigned short f2bf(float f){
    unsigned u = __float_as_uint(f);
    u += 0x7fffu + ((u>>16)&1u);
    return (unsigned short)(u>>16);
}
__device__ __forceinline__ float bf2f(unsigned short s){
    return __uint_as_float(((unsigned)s)<<16);
}
// pack two f32 -> 2 x bf16 in one dword (RNE)
__device__ __forceinline__ unsigned cvt_pk_bf16(float lo, float hi){
    unsigned r;
    asm("v_cvt_pk_bf16_f32 %0, %1, %2" : "=v"(r) : "v"(lo), "v"(hi));
    return r;
}

// Wave 0: consumer (serial recurrence, 16 seqs across MFMA columns).
// Waves 1,2: producers (stream X, exp, stage into LDS chunks).
// amdgpu_waves_per_eu(1): grant the full unified register budget (~512) so the
// consumer's Ef[8][4] (128 VGPRs of loop-invariant exp(trans) A-frags) stays
// in registers. Round-1 failure mode: heuristic capped at 156 VGPRs and
// spilled Ef to scratch (WRITE_SIZE 769 KB), ~2000 cy/step of reloads.
__global__ __attribute__((amdgpu_flat_work_group_size(192, 192), amdgpu_waves_per_eu(1)))
void crf_nll_kernel(const float* __restrict__ X,
                    const int*   __restrict__ y,
                    const float* __restrict__ trans,
                    float* __restrict__ out, int L, int B)
{
    const int g    = blockIdx.x;
    const int tid  = threadIdx.x;
    const int w    = tid >> 6;
    const int lane = tid & 63;
    const int b0   = g * NSEQ;

    // emis[buf][s][n][k] f32, k-bytes XOR-swizzled by ((n&7)<<4)   : 48 KB
    __shared__ __align__(16) float          emis[2][CH][NSEQ][RN];
    // pbuf[buf][n][k] bf16, k-bytes XOR-swizzled by ((n&7)<<4)     :  8 KB
    __shared__ __align__(16) unsigned short pbuf[2][NSEQ][RN];
    __shared__ float goldsh[NSEQ];

    const int nch = (L + CH - 1) / CH;

    // ---------------- common prologue: gold score + p init ----------------
    if (tid < NSEQ) goldsh[tid] = 0.f;
    {
        unsigned short* pr = &pbuf[0][0][0];
        for (int i = tid; i < 2*NSEQ*RN; i += 192) pr[i] = 0;
    }
    __syncthreads();
    {
        const int n = tid & 15, stripe = tid >> 4;   // 12 t-stripes x 16 seqs
        int b = b0 + n; if (b >= B) b = B - 1;
        const int*   yb = y + (size_t)b * L;
        const float* Xb = X + (size_t)b * L * RN;
        float gacc = 0.f;
        for (int t = stripe; t < L; t += 12) {
            int yt = yb[t];
            int yp = t ? yb[t-1] : START_T;
            gacc += trans[yt*RN + yp] + Xb[(size_t)t*RN + yt];
        }
        if (stripe == 0) gacc += trans[END_T*RN + yb[L-1]];
        atomicAdd(&goldsh[n], gacc);
    }
    if (tid < NSEQ) {   // seed p0[n][START] = 1.0 (swizzled position)
        char* base = (char*)&pbuf[0][0][0];
        *(unsigned short*)(base + (tid<<8) + ((2*START_T) ^ ((tid&7)<<4))) = (unsigned short)0x3F80;
    }
    __syncthreads();

    if (w == 0) {
        // ========================= CONSUMER =========================
        const int n = lane & 15;      // MFMA column = sequence within group
        const int q = lane >> 4;      // k/row quad
        const int x = (n & 7) << 4;   // LDS swizzle

        // E = exp(trans) A-frags resident in VGPRs: A[m=16T+n][k=32c+8q+j]
        v8s Ef[8][4];
        #pragma unroll
        for (int T = 0; T < 8; ++T) {
            #pragma unroll
            for (int cc = 0; cc < 4; ++cc) {
                const float* tr = trans + (size_t)(16*T + n)*RN + 32*cc + 8*q;
                float4 u0 = *(const float4*)(tr);
                float4 u1 = *(const float4*)(tr + 4);
                v8s v;
                v[0]=(short)f2bf(__expf(u0.x)); v[1]=(short)f2bf(__expf(u0.y));
                v[2]=(short)f2bf(__expf(u0.z)); v[3]=(short)f2bf(__expf(u0.w));
                v[4]=(short)f2bf(__expf(u1.x)); v[5]=(short)f2bf(__expf(u1.y));
                v[6]=(short)f2bf(__expf(u1.z)); v[7]=(short)f2bf(__expf(u1.w));
                Ef[T][cc] = v;
            }
        }

        // precomputed lane-invariant LDS byte offsets (XOR split into disjoint bit fields)
        int prd[4], pwr[8], eof[8];
        #pragma unroll
        for (int cc = 0; cc < 4; ++cc)                    // read k=32cc+8q (16B)
            prd[cc] = n*256 + (64*cc ^ (x & 64)) + ((16*q) ^ (x & 48));
        #pragma unroll
        for (int T = 0; T < 8; ++T) {
            pwr[T] = n*256 + (32*T ^ (x & 0x60)) + ((8*q) ^ (x & 0x10)); // write k=16T+4q (8B)
            eof[T] = n*512 + (64*T ^ (x & 64)) + ((16*q) ^ (x & 48));    // emis k=16T+4q (16B f32)
        }

        char* pb_base = (char*)&pbuf[0][0][0];
        char* em_base = (char*)&emis[0][0][0][0];

        float logscale = 0.f, mxf = 1.f, invv = 1.f;

        for (int c = 0; c < nch; ++c) {
            asm volatile("" ::: "memory");
            __builtin_amdgcn_s_barrier();          // chunk c staged by producers
            asm volatile("" ::: "memory");
            char* emc = em_base + (c & 1) * (CH*NSEQ*RN*4);
            #pragma unroll
            for (int s = 0; s < CH; ++s) {
                const int t = c*CH + s;
                if (t >= L) break;
                char* prb = pb_base + (t & 1) * 4096;
                char* pwb = pb_base + ((t + 1) & 1) * 4096;
                char* emb = emc + s * (NSEQ*RN*4);

                v8s Bf0 = *(const v8s*)(prb + prd[0]);
                v8s Bf1 = *(const v8s*)(prb + prd[1]);
                v8s Bf2 = *(const v8s*)(prb + prd[2]);
                v8s Bf3 = *(const v8s*)(prb + prd[3]);

                const bool mstep = ((t & 3) == 1);   // measure per-column max
                const bool astep = ((t & 3) == 2);   // apply (stale-by-one)
                if (astep) { invv = 1.0f / mxf; logscale += __logf(mxf); }
                float vmax = 0.f;

                // two halves of 4 T-tiles: halves peak register pressure
                // (acc 16 + ev 16 live instead of 32 + 32)
                #pragma unroll
                for (int H = 0; H < 2; ++H) {
                    const int Tb = 4 * H;
                    v4f a0 = {0.f,0.f,0.f,0.f};
                    v4f a1 = {0.f,0.f,0.f,0.f};
                    v4f a2 = {0.f,0.f,0.f,0.f};
                    v4f a3 = {0.f,0.f,0.f,0.f};
                    a0 = __builtin_amdgcn_mfma_f32_16x16x32_bf16(Ef[Tb+0][0], Bf0, a0, 0,0,0);
                    a1 = __builtin_amdgcn_mfma_f32_16x16x32_bf16(Ef[Tb+1][0], Bf0, a1, 0,0,0);
                    a2 = __builtin_amdgcn_mfma_f32_16x16x32_bf16(Ef[Tb+2][0], Bf0, a2, 0,0,0);
                    a3 = __builtin_amdgcn_mfma_f32_16x16x32_bf16(Ef[Tb+3][0], Bf0, a3, 0,0,0);
                    a0 = __builtin_amdgcn_mfma_f32_16x16x32_bf16(Ef[Tb+0][1], Bf1, a0, 0,0,0);
                    a1 = __builtin_amdgcn_mfma_f32_16x16x32_bf16(Ef[Tb+1][1], Bf1, a1, 0,0,0);
                    a2 = __builtin_amdgcn_mfma_f32_16x16x32_bf16(Ef[Tb+2][1], Bf1, a2, 0,0,0);
                    a3 = __builtin_amdgcn_mfma_f32_16x16x32_bf16(Ef[Tb+3][1], Bf1, a3, 0,0,0);
                    a0 = __builtin_amdgcn_mfma_f32_16x16x32_bf16(Ef[Tb+0][2], Bf2, a0, 0,0,0);
                    a1 = __builtin_amdgcn_mfma_f32_16x16x32_bf16(Ef[Tb+1][2], Bf2, a1, 0,0,0);
                    a2 = __builtin_amdgcn_mfma_f32_16x16x32_bf16(Ef[Tb+2][2], Bf2, a2, 0,0,0);
                    a3 = __builtin_amdgcn_mfma_f32_16x16x32_bf16(Ef[Tb+3][2], Bf2, a3, 0,0,0);
                    a0 = __builtin_amdgcn_mfma_f32_16x16x32_bf16(Ef[Tb+0][3], Bf3, a0, 0,0,0);
                    a1 = __builtin_amdgcn_mfma_f32_16x16x32_bf16(Ef[Tb+1][3], Bf3, a1, 0,0,0);
                    a2 = __builtin_amdgcn_mfma_f32_16x16x32_bf16(Ef[Tb+2][3], Bf3, a2, 0,0,0);
                    a3 = __builtin_amdgcn_mfma_f32_16x16x32_bf16(Ef[Tb+3][3], Bf3, a3, 0,0,0);

                    float4 e0 = *(const float4*)(emb + eof[Tb+0]);
                    float4 e1 = *(const float4*)(emb + eof[Tb+1]);
                    float4 e2 = *(const float4*)(emb + eof[Tb+2]);
                    float4 e3 = *(const float4*)(emb + eof[Tb+3]);

                    {
                        float o0 = a0[0]*e0.x, o1 = a0[1]*e0.y, o2 = a0[2]*e0.z, o3 = a0[3]*e0.w;
                        if (astep) { o0*=invv; o1*=invv; o2*=invv; o3*=invv; }
                        if (mstep) vmax = fmaxf(vmax, fmaxf(fmaxf(o0,o1), fmaxf(o2,o3)));
                        uint2 dd; dd.x = cvt_pk_bf16(o0,o1); dd.y = cvt_pk_bf16(o2,o3);
                        *(uint2*)(pwb + pwr[Tb+0]) = dd;
                    }
                    {
                        float o0 = a1[0]*e1.x, o1 = a1[1]*e1.y, o2 = a1[2]*e1.z, o3 = a1[3]*e1.w;
                        if (astep) { o0*=invv; o1*=invv; o2*=invv; o3*=invv; }
                        if (mstep) vmax = fmaxf(vmax, fmaxf(fmaxf(o0,o1), fmaxf(o2,o3)));
                        uint2 dd; dd.x = cvt_pk_bf16(o0,o1); dd.y = cvt_pk_bf16(o2,o3);
                        *(uint2*)(pwb + pwr[Tb+1]) = dd;
                    }
                    {
                        float o0 = a2[0]*e2.x, o1 = a2[1]*e2.y, o2 = a2[2]*e2.z, o3 = a2[3]*e2.w;
                        if (astep) { o0*=invv; o1*=invv; o2*=invv; o3*=invv; }
                        if (mstep) vmax = fmaxf(vmax, fmaxf(fmaxf(o0,o1), fmaxf(o2,o3)));
                        uint2 dd; dd.x = cvt_pk_bf16(o0,o1); dd.y = cvt_pk_bf16(o2,o3);
                        *(uint2*)(pwb + pwr[Tb+2]) = dd;
                    }
                    {
                        float o0 = a3[0]*e3.x, o1 = a3[1]*e3.y, o2 = a3[2]*e3.z, o3 = a3[3]*e3.w;
                        if (astep) { o0*=invv; o1*=invv; o2*=invv; o3*=invv; }
                        if (mstep) vmax = fmaxf(vmax, fmaxf(fmaxf(o0,o1), fmaxf(o2,o3)));
                        uint2 dd; dd.x = cvt_pk_bf16(o0,o1); dd.y = cvt_pk_bf16(o2,o3);
                        *(uint2*)(pwb + pwr[Tb+3]) = dd;
                    }
                }
                if (mstep) {   // per-column (per-sequence) max across the 4 quads
                    float m1 = fmaxf(vmax, __shfl_xor(vmax, 16, 64));
                    mxf = fmaxf(m1, __shfl_xor(m1, 32, 64));
                }
            }
        }

        // ---------------- logZ epilogue ----------------
        char* pfbase = pb_base + (L & 1) * 4096;
        float zacc = 0.f;
        #pragma unroll
        for (int u = 0; u < 4; ++u) {
            int off = n*256 + (64*q ^ (x & 64)) + ((16*u) ^ (x & 48));
            v8s pv = *(const v8s*)(pfbase + off);
            #pragma unroll
            for (int j = 0; j < 8; ++j) {
                int k = 32*q + 8*u + j;
                zacc += bf2f((unsigned short)pv[j]) * __expf(trans[END_T*RN + k]);
            }
        }
        zacc += __shfl_xor(zacc, 16, 64);
        zacc += __shfl_xor(zacc, 32, 64);
        if (q == 0 && (b0 + n) < B)
            out[b0 + n] = logscale + __logf(zacc) - goldsh[n];
    } else {
        // ========================= PRODUCERS (w = 1,2) =========================
        const int pidx = w - 1;
        float4 RA[12], RB[12];    // two chunks in flight; ping-pong is fully static
                                  // (no runtime-selected register arrays — rule #20)

        auto issue_chunk = [&](int c, float4* R) {
            #pragma unroll
            for (int i = 0; i < 12; ++i) {
                int f  = i*128 + pidx*64 + lane;            // (s,n,tq) flat over CH*16*32
                int s  = f >> 9, rem = f & 511, nn = rem >> 5, tq = rem & 31;
                int t  = c*CH + s; if (t >= L) t = L - 1;   // clamped tail (unused)
                int b  = b0 + nn; if (b >= B) b = B - 1;
                R[i] = *(const float4*)(X + (size_t)b*L*RN + (size_t)t*RN + 4*tq);
            }
        };
        auto expwrite_chunk = [&](int c, const float4* R) {
            char* emc = (char*)&emis[0][0][0][0] + (c & 1)*(CH*NSEQ*RN*4);
            #pragma unroll
            for (int i = 0; i < 12; ++i) {
                int f  = i*128 + pidx*64 + lane;
                int s  = f >> 9, rem = f & 511, nn = rem >> 5, tq = rem & 31;
                float4 v = R[i];
                float4 e;
                e.x = __expf(v.x); e.y = __expf(v.y);
                e.z = __expf(v.z); e.w = __expf(v.w);
                *(float4*)(emc + s*(NSEQ*RN*4) + nn*512 + ((16*tq) ^ ((nn&7)<<4))) = e;
            }
        };

        issue_chunk(0, RA);
        if (nch > 1) issue_chunk(1, RB);
        expwrite_chunk(0, RA);

        for (int c = 0; c < nch; c += 2) {
            // drain only LDS (writes visible to consumer); vmcnt prefetch stays in flight
            asm volatile("s_waitcnt lgkmcnt(0)" ::: "memory");
            __builtin_amdgcn_s_barrier();
            asm volatile("" ::: "memory");
            if (c + 2 < nch) issue_chunk(c + 2, RA);
            if (c + 1 < nch) expwrite_chunk(c + 1, RB);
            if (c + 1 < nch) {
                asm volatile("s_waitcnt lgkmcnt(0)" ::: "memory");
                __builtin_amdgcn_s_barrier();
                asm volatile("" ::: "memory");
                if (c + 3 < nch) issue_chunk(c + 3, RB);
                if (c + 2 < nch) expwrite_chunk(c + 2, RA);
            }
        }
    }
}

extern "C" void kernel_launch(void* const* d_in, const int* in_sizes, int n_in,
                              void* d_out, int out_size, void* d_ws, size_t ws_size,
                              hipStream_t stream) {
    const float* X     = (const float*)d_in[0];
    const int*   y     = (const int*)d_in[1];
    const float* trans = (const float*)d_in[2];
    float*       out   = (float*)d_out;

    const int B = out_size;            // 256
    const int L = in_sizes[1] / B;     // 1024

    const int blocks = (B + NSEQ - 1) / NSEQ;   // 16
    crf_nll_kernel<<<dim3(blocks), dim3(192), 0, stream>>>(X, y, trans, out, L, B);
}